// Round 1
// baseline (1987.234 us; speedup 1.0000x reference)
//
#include <hip/hip_runtime.h>

#define BB  128
#define TT  256
#define CCH 384
#define NHH 6
#define HSZ 64
#define BTT (BB*TT)

typedef unsigned short u16;
typedef unsigned int   u32;

__device__ __forceinline__ float bflo(u32 w) { union { u32 i; float f; } v; v.i = w << 16; return v.f; }
__device__ __forceinline__ float bfhi(u32 w) { union { u32 i; float f; } v; v.i = w & 0xffff0000u; return v.f; }
__device__ __forceinline__ u16 f2bf(float f) {
  union { float f; u32 i; } v; v.f = f; u32 x = v.i;
  return (u16)((x + 0x7fffu + ((x >> 16) & 1u)) >> 16);
}

// ---------------- LayerNorm: fp32 in -> bf16 out, one wave per row ----------------
__global__ __launch_bounds__(64) void ln_kernel(const float* __restrict__ x,
                                                const float* __restrict__ g,
                                                const float* __restrict__ b,
                                                u16* __restrict__ out) {
  int row = blockIdx.x;
  int lane = threadIdx.x;
  const float* xr = x + (size_t)row * CCH;
  float vals[6];
  float sum = 0.f;
#pragma unroll
  for (int i = 0; i < 6; ++i) { vals[i] = xr[lane + (i << 6)]; sum += vals[i]; }
#pragma unroll
  for (int off = 32; off; off >>= 1) sum += __shfl_xor(sum, off);
  float mean = sum * (1.f / 384.f);
  float vs = 0.f;
#pragma unroll
  for (int i = 0; i < 6; ++i) { float d = vals[i] - mean; vs += d * d; }
#pragma unroll
  for (int off = 32; off; off >>= 1) vs += __shfl_xor(vs, off);
  float rinv = rsqrtf(vs * (1.f / 384.f) + 1e-5f);
  u16* orow = out + (size_t)row * CCH;
#pragma unroll
  for (int i = 0; i < 6; ++i) {
    int c = lane + (i << 6);
    orow[c] = f2bf((vals[i] - mean) * rinv * g[c] + b[c]);
  }
}

// ---------------- weight repacks ----------------
__global__ void cast_kernel(const float* __restrict__ in, u16* __restrict__ out, int n) {
  int i = blockIdx.x * 256 + threadIdx.x;
  if (i < n) out[i] = f2bf(in[i]);
}

// wq (H,C,HS) -> (C rows x C cols) with col j = h*64+d
__global__ void repack_qkv(const float* __restrict__ wq, const float* __restrict__ wk,
                           const float* __restrict__ wv, u16* __restrict__ oq,
                           u16* __restrict__ ok, u16* __restrict__ ov) {
  int idx = blockIdx.x * 256 + threadIdx.x;
  if (idx >= CCH * CCH) return;
  int c = idx / CCH, j = idx % CCH;
  int h = j >> 6, d = j & 63;
  size_t src = ((size_t)h * CCH + c) * 64 + d;
  oq[idx] = f2bf(wq[src]);
  ok[idx] = f2bf(wk[src]);
  ov[idx] = f2bf(wv[src]);
}

// ---------------- GEMM: bf16 A(MxK) x bf16 B(KxN) -> fp32/bf16, 64x64x16 tiles ----------------
template <int BIAS, int RES, int RELU, int OUTBF>
__global__ __launch_bounds__(256) void gemm_bf16(const u16* __restrict__ A,
                                                 const u16* __restrict__ Bm,
                                                 const float* __restrict__ bias,
                                                 const float* __restrict__ res,
                                                 void* __restrict__ outv,
                                                 int M, int N, int K) {
  __shared__ float As[16][68];
  __shared__ float Bs[16][68];
  int tid = threadIdx.x;
  int tx = tid & 15, ty = tid >> 4;
  int m0 = blockIdx.y * 64, n0 = blockIdx.x * 64;
  int arow = tid >> 2, akq = (tid & 3) << 2;
  int brow = tid >> 4, bcg = (tid & 15) << 2;
  float acc[4][4];
#pragma unroll
  for (int i = 0; i < 4; ++i)
#pragma unroll
    for (int j = 0; j < 4; ++j) acc[i][j] = 0.f;

  const u16* aptr = A + (size_t)(m0 + arow) * K + akq;
  const u16* bptr = Bm + (size_t)brow * N + n0 + bcg;

  for (int k0 = 0; k0 < K; k0 += 16) {
    ushort4 a4 = *(const ushort4*)(aptr + k0);
    ushort4 b4 = *(const ushort4*)(bptr + (size_t)k0 * N);
    __syncthreads();
    As[akq + 0][arow] = bflo((u32)a4.x);
    As[akq + 1][arow] = bflo((u32)a4.y);
    As[akq + 2][arow] = bflo((u32)a4.z);
    As[akq + 3][arow] = bflo((u32)a4.w);
    float4 bf4;
    bf4.x = bflo((u32)b4.x); bf4.y = bflo((u32)b4.y);
    bf4.z = bflo((u32)b4.z); bf4.w = bflo((u32)b4.w);
    *(float4*)&Bs[brow][bcg] = bf4;
    __syncthreads();
#pragma unroll
    for (int kk = 0; kk < 16; ++kk) {
      float4 av = *(const float4*)&As[kk][ty << 2];
      float4 bv = *(const float4*)&Bs[kk][tx << 2];
      acc[0][0] += av.x * bv.x; acc[0][1] += av.x * bv.y; acc[0][2] += av.x * bv.z; acc[0][3] += av.x * bv.w;
      acc[1][0] += av.y * bv.x; acc[1][1] += av.y * bv.y; acc[1][2] += av.y * bv.z; acc[1][3] += av.y * bv.w;
      acc[2][0] += av.z * bv.x; acc[2][1] += av.z * bv.y; acc[2][2] += av.z * bv.z; acc[2][3] += av.z * bv.w;
      acc[3][0] += av.w * bv.x; acc[3][1] += av.w * bv.y; acc[3][2] += av.w * bv.z; acc[3][3] += av.w * bv.w;
    }
  }

#pragma unroll
  for (int i = 0; i < 4; ++i) {
    int row = m0 + (ty << 2) + i;
    int col = n0 + (tx << 2);
    float4 r;
    r.x = acc[i][0]; r.y = acc[i][1]; r.z = acc[i][2]; r.w = acc[i][3];
    if (BIAS) {
      float4 bb = *(const float4*)(bias + col);
      r.x += bb.x; r.y += bb.y; r.z += bb.z; r.w += bb.w;
    }
    if (RES) {
      float4 rr = *(const float4*)(res + (size_t)row * N + col);
      r.x += rr.x; r.y += rr.y; r.z += rr.z; r.w += rr.w;
    }
    if (RELU) {
      r.x = fmaxf(r.x, 0.f); r.y = fmaxf(r.y, 0.f);
      r.z = fmaxf(r.z, 0.f); r.w = fmaxf(r.w, 0.f);
    }
    if (OUTBF) {
      ushort4 o;
      o.x = f2bf(r.x); o.y = f2bf(r.y); o.z = f2bf(r.z); o.w = f2bf(r.w);
      *(ushort4*)((u16*)outv + (size_t)row * N + col) = o;
    } else {
      *(float4*)((float*)outv + (size_t)row * N + col) = r;
    }
  }
}

// ---------------- attention: one block per (b,h); column softmax (query axis) ----------------
// scale = C^-0.5 per reference. q,k,v,out: (B*T x C) bf16 with col = h*64+d.
#define ASCALE 0.051031036307982884f

__global__ __launch_bounds__(256) void attn_kernel(const u16* __restrict__ q,
                                                   const u16* __restrict__ k,
                                                   const u16* __restrict__ v,
                                                   u16* __restrict__ out) {
  int b = blockIdx.x / NHH, h = blockIdx.x % NHH;
  size_t base = ((size_t)b * TT) * CCH + h * HSZ;
  int tid = threadIdx.x;
  __shared__ float m_sh[TT];
  __shared__ float linv_sh[TT];

  // ---- pass 1: column stats. thread = column s; m_s/l_s over t in [s, T) ----
  {
    int s = tid;
    float kr[HSZ];
    const u32* kp = (const u32*)(k + base + (size_t)s * CCH);
#pragma unroll
    for (int i = 0; i < HSZ / 2; ++i) { u32 w = kp[i]; kr[2 * i] = bflo(w); kr[2 * i + 1] = bfhi(w); }
    float m = -1e30f, l = 0.f;
    int t0 = __builtin_amdgcn_readfirstlane(tid & ~63);  // wave-uniform start
    for (int t = t0; t < TT; ++t) {
      const u32* qp = (const u32*)(q + base + (size_t)t * CCH);  // wave-uniform row
      float dot = 0.f;
#pragma unroll
      for (int i = 0; i < HSZ / 2; ++i) {
        u32 w = qp[i];
        dot += bflo(w) * kr[2 * i] + bfhi(w) * kr[2 * i + 1];
      }
      if (t >= s) {
        float xv = dot * ASCALE;
        float mn = fmaxf(m, xv);
        l = l * __expf(m - mn) + __expf(xv - mn);
        m = mn;
      }
    }
    m_sh[s] = m;
    linv_sh[s] = 1.f / l;
  }
  __syncthreads();

  // ---- pass 2: thread = row t; O[t,:] = sum_{s<=t} exp(S[t,s]-m_s)/l_s * v[s,:] ----
  {
    int t = tid;
    float qr[HSZ];
    const u32* qp = (const u32*)(q + base + (size_t)t * CCH);
#pragma unroll
    for (int i = 0; i < HSZ / 2; ++i) { u32 w = qp[i]; qr[2 * i] = bflo(w); qr[2 * i + 1] = bfhi(w); }
    float acc[HSZ];
#pragma unroll
    for (int d = 0; d < HSZ; ++d) acc[d] = 0.f;
    int smax = __builtin_amdgcn_readfirstlane(tid | 63);  // wave-uniform bound
    for (int s = 0; s <= smax; ++s) {
      const u32* kp = (const u32*)(k + base + (size_t)s * CCH);  // uniform
      float dot = 0.f;
#pragma unroll
      for (int i = 0; i < HSZ / 2; ++i) {
        u32 w = kp[i];
        dot += bflo(w) * qr[2 * i] + bfhi(w) * qr[2 * i + 1];
      }
      if (s <= t) {
        float p = __expf(dot * ASCALE - m_sh[s]) * linv_sh[s];
        const u32* vp = (const u32*)(v + base + (size_t)s * CCH);  // uniform
#pragma unroll
        for (int i = 0; i < HSZ / 2; ++i) {
          u32 w = vp[i];
          acc[2 * i] += p * bflo(w);
          acc[2 * i + 1] += p * bfhi(w);
        }
      }
    }
    u16* op = out + base + (size_t)t * CCH;
#pragma unroll
    for (int d = 0; d < HSZ; ++d) op[d] = f2bf(acc[d]);
  }
}

// ---------------- launch ----------------
extern "C" void kernel_launch(void* const* d_in, const int* in_sizes, int n_in,
                              void* d_out, int out_size, void* d_ws, size_t ws_size,
                              hipStream_t stream) {
  const float* x     = (const float*)d_in[0];
  const float* wq    = (const float*)d_in[1];
  const float* wk    = (const float*)d_in[2];
  const float* wv    = (const float*)d_in[3];
  const float* wproj = (const float*)d_in[4];
  const float* bproj = (const float*)d_in[5];
  const float* w1    = (const float*)d_in[6];
  const float* b1    = (const float*)d_in[7];
  const float* w2    = (const float*)d_in[8];
  const float* b2    = (const float*)d_in[9];
  const float* ln1g  = (const float*)d_in[10];
  const float* ln1b  = (const float*)d_in[11];
  const float* ln2g  = (const float*)d_in[12];
  const float* ln2b  = (const float*)d_in[13];
  float* out = (float*)d_out;

  char* ws = (char*)d_ws;
  size_t off = 0;
  auto alloc = [&](size_t bytes) -> void* {
    void* p = ws + off;
    off += (bytes + 255) & ~(size_t)255;
    return p;
  };

  const size_t act_c_b  = (size_t)BTT * CCH * 2;   // bf16 (B*T x C)
  const size_t act_c_f  = (size_t)BTT * CCH * 4;   // fp32 (B*T x C)

  u16* wq_b    = (u16*)alloc((size_t)CCH * CCH * 2);
  u16* wk_b    = (u16*)alloc((size_t)CCH * CCH * 2);
  u16* wv_b    = (u16*)alloc((size_t)CCH * CCH * 2);
  u16* wproj_b = (u16*)alloc((size_t)CCH * CCH * 2);
  u16* w1_b    = (u16*)alloc((size_t)CCH * 4 * CCH * 2);
  u16* w2_b    = (u16*)alloc((size_t)4 * CCH * CCH * 2);

  u16*   h_b    = (u16*)alloc(act_c_b);    // also reused as attn_b
  u16*   q_b    = (u16*)alloc(act_c_b);    // also reused as h2_b
  float* x2     = (float*)alloc(act_c_f);
  u16*   k_b    = (u16*)alloc(act_c_b);    // u_b starts here (k,v dead by then)
  u16*   v_b    = (u16*)alloc(act_c_b);
  (void)alloc(act_c_f);                    // tail of u_b
  u16* attn_b = h_b;
  u16* h2_b   = q_b;
  u16* u_b    = k_b;                        // spans k_b + v_b + tail = BT*1536 bf16

  (void)in_sizes; (void)n_in; (void)out_size; (void)ws_size;

  // weight repacks (cheap; redone every call for graph-capture safety)
  repack_qkv<<<(CCH * CCH + 255) / 256, 256, 0, stream>>>(wq, wk, wv, wq_b, wk_b, wv_b);
  cast_kernel<<<(CCH * CCH + 255) / 256, 256, 0, stream>>>(wproj, wproj_b, CCH * CCH);
  cast_kernel<<<(CCH * 4 * CCH + 255) / 256, 256, 0, stream>>>(w1, w1_b, CCH * 4 * CCH);
  cast_kernel<<<(4 * CCH * CCH + 255) / 256, 256, 0, stream>>>(w2, w2_b, 4 * CCH * CCH);

  // LN1
  ln_kernel<<<BTT, 64, 0, stream>>>(x, ln1g, ln1b, h_b);

  // QKV projections
  dim3 g384(CCH / 64, BTT / 64);
  gemm_bf16<0, 0, 0, 1><<<g384, 256, 0, stream>>>(h_b, wq_b, nullptr, nullptr, q_b, BTT, CCH, CCH);
  gemm_bf16<0, 0, 0, 1><<<g384, 256, 0, stream>>>(h_b, wk_b, nullptr, nullptr, k_b, BTT, CCH, CCH);
  gemm_bf16<0, 0, 0, 1><<<g384, 256, 0, stream>>>(h_b, wv_b, nullptr, nullptr, v_b, BTT, CCH, CCH);

  // attention (writes attn_b == h_b; h dead now)
  attn_kernel<<<BB * NHH, 256, 0, stream>>>(q_b, k_b, v_b, attn_b);

  // x2 = x + attn @ wproj + bproj
  gemm_bf16<1, 1, 0, 0><<<g384, 256, 0, stream>>>(attn_b, wproj_b, bproj, x, x2, BTT, CCH, CCH);

  // LN2 (writes h2_b == q_b; q dead now)
  ln_kernel<<<BTT, 64, 0, stream>>>(x2, ln2g, ln2b, h2_b);

  // u = relu(h2 @ w1 + b1)   (writes u_b over k_b/v_b; dead now)
  dim3 g1536(4 * CCH / 64, BTT / 64);
  gemm_bf16<1, 0, 1, 1><<<g1536, 256, 0, stream>>>(h2_b, w1_b, b1, nullptr, u_b, BTT, 4 * CCH, CCH);

  // out = x2 + u @ w2 + b2
  gemm_bf16<1, 1, 0, 0><<<g384, 256, 0, stream>>>(u_b, w2_b, b2, x2, out, BTT, CCH, 4 * CCH);
}

// Round 2
// 431.983 us; speedup vs baseline: 4.6003x; 4.6003x over previous
//
#include <hip/hip_runtime.h>

#define BB 128
#define TT 256
#define CCH 384
#define NHH 6
#define HSZ 64
#define BTT (BB*TT)
#define QKVLD 1152

typedef unsigned short u16;
typedef unsigned int   u32;
typedef __attribute__((ext_vector_type(8))) short  short8;   // 8 x bf16 (4 VGPR)
typedef __attribute__((ext_vector_type(4))) float  floatx4;  // MFMA C/D

__device__ __forceinline__ u16 f2bf(float f) {
  union { float f; u32 i; } v; v.f = f; u32 x = v.i;
  return (u16)((x + 0x7fffu + ((x >> 16) & 1u)) >> 16);
}

// async global->LDS, 16B per lane; LDS dest is wave-uniform base + lane*16
__device__ __forceinline__ void gll16(const u16* g, u16* l) {
  __builtin_amdgcn_global_load_lds((const __attribute__((address_space(1))) void*)g,
                                   (__attribute__((address_space(3))) void*)l, 16, 0, 0);
}

// ---------------- LayerNorm: fp32 in -> bf16 out, one wave per row ----------------
__global__ __launch_bounds__(64) void ln_kernel(const float* __restrict__ x,
                                                const float* __restrict__ g,
                                                const float* __restrict__ b,
                                                u16* __restrict__ out) {
  int row = blockIdx.x;
  int lane = threadIdx.x;
  const float* xr = x + (size_t)row * CCH;
  float vals[6];
  float sum = 0.f;
#pragma unroll
  for (int i = 0; i < 6; ++i) { vals[i] = xr[lane + (i << 6)]; sum += vals[i]; }
#pragma unroll
  for (int off = 32; off; off >>= 1) sum += __shfl_xor(sum, off);
  float mean = sum * (1.f / 384.f);
  float vs = 0.f;
#pragma unroll
  for (int i = 0; i < 6; ++i) { float d = vals[i] - mean; vs += d * d; }
#pragma unroll
  for (int off = 32; off; off >>= 1) vs += __shfl_xor(vs, off);
  float rinv = rsqrtf(vs * (1.f / 384.f) + 1e-5f);
  u16* orow = out + (size_t)row * CCH;
#pragma unroll
  for (int i = 0; i < 6; ++i) {
    int c = lane + (i << 6);
    orow[c] = f2bf((vals[i] - mean) * rinv * g[c] + b[c]);
  }
}

// ---------------- weight repacks: (K,N) fp32 -> (N,K) bf16 ----------------
__global__ void repack_t(const float* __restrict__ in, u16* __restrict__ out, int K, int N) {
  int idx = blockIdx.x * 256 + threadIdx.x;
  if (idx >= K * N) return;
  int n = idx / K, kk = idx % K;
  out[idx] = f2bf(in[(size_t)kk * N + n]);
}

// wq/wk/wv (H,C,HS) -> rows n=h*64+d of (384,384), into one (1152,384) buffer
__global__ void repack_qkv_t(const float* __restrict__ wq, const float* __restrict__ wk,
                             const float* __restrict__ wv, u16* __restrict__ o) {
  int idx = blockIdx.x * 256 + threadIdx.x;
  if (idx >= CCH * CCH) return;
  int n = idx / CCH, kk = idx % CCH;
  size_t src = ((size_t)(n >> 6) * CCH + kk) * 64 + (n & 63);
  o[idx]                 = f2bf(wq[src]);
  o[idx + CCH * CCH]     = f2bf(wk[src]);
  o[idx + 2 * CCH * CCH] = f2bf(wv[src]);
}

// ---------------- MFMA GEMM: C[M,N] = A[M,K] * W[N,K]^T, 128x128 tile, BK=32 ----------------
template <int BIAS, int RES, int RELU, int OUTBF>
__global__ __launch_bounds__(256) void gemm_mfma(const u16* __restrict__ A,
                                                 const u16* __restrict__ W,
                                                 const float* __restrict__ bias,
                                                 const float* __restrict__ res,
                                                 void* __restrict__ outv,
                                                 int M, int N, int K) {
  __shared__ __align__(16) u16 As[128 * 32];
  __shared__ __align__(16) u16 Bs[128 * 32];
  const int tid = threadIdx.x;
  const int lane = tid & 63;
  const int w = tid >> 6;
  const int wr = w >> 1, wc = w & 1;
  const int m0 = blockIdx.y * 128, n0 = blockIdx.x * 128;
  const int lm = lane & 15, qd = lane >> 4;

  floatx4 acc[4][4];
  floatx4 zero4 = {0.f, 0.f, 0.f, 0.f};
#pragma unroll
  for (int i = 0; i < 4; ++i)
#pragma unroll
    for (int j = 0; j < 4; ++j) acc[i][j] = zero4;

  // loader: wave w stages rows [32w,32w+32) of both tiles; slot = lane&3,
  // fetched global 16B-chunk = slot ^ ((row>>1)&3)  (XOR swizzle, loader-compatible)
  const int r0 = w * 32 + (lane >> 2);
  const int c0 = (lane & 3) ^ ((r0 >> 1) & 3);
  const int r1 = r0 + 16;
  const int c1 = (lane & 3) ^ ((r1 >> 1) & 3);
  const u16* a0 = A + (size_t)(m0 + r0) * K + c0 * 8;
  const u16* a1 = A + (size_t)(m0 + r1) * K + c1 * 8;
  const u16* b0 = W + (size_t)(n0 + r0) * K + c0 * 8;
  const u16* b1 = W + (size_t)(n0 + r1) * K + c1 * 8;
  u16* dA0 = &As[w * 1024];
  u16* dA1 = &As[w * 1024 + 512];
  u16* dB0 = &Bs[w * 1024];
  u16* dB1 = &Bs[w * 1024 + 512];

  for (int k0 = 0; k0 < K; k0 += 32) {
    __syncthreads();
    gll16(a0 + k0, dA0);
    gll16(a1 + k0, dA1);
    gll16(b0 + k0, dB0);
    gll16(b1 + k0, dB1);
    __syncthreads();
    short8 af[4], bf[4];
#pragma unroll
    for (int i = 0; i < 4; ++i) {
      int rm = 64 * wr + 16 * i + lm;
      af[i] = *(const short8*)&As[rm * 32 + (qd ^ ((rm >> 1) & 3)) * 8];
      int rn = 64 * wc + 16 * i + lm;
      bf[i] = *(const short8*)&Bs[rn * 32 + (qd ^ ((rn >> 1) & 3)) * 8];
    }
#pragma unroll
    for (int i = 0; i < 4; ++i)
#pragma unroll
      for (int j = 0; j < 4; ++j)
        acc[i][j] = __builtin_amdgcn_mfma_f32_16x16x32_bf16(af[i], bf[j], acc[i][j], 0, 0, 0);
  }

  // epilogue: C/D layout col=lm, row=qd*4+r
#pragma unroll
  for (int i = 0; i < 4; ++i) {
    int row0 = m0 + 64 * wr + 16 * i + qd * 4;
#pragma unroll
    for (int j = 0; j < 4; ++j) {
      int col = n0 + 64 * wc + 16 * j + lm;
      float bb = 0.f;
      if (BIAS) bb = bias[col];
#pragma unroll
      for (int r = 0; r < 4; ++r) {
        size_t idx = (size_t)(row0 + r) * N + col;
        float val = acc[i][j][r] + bb;
        if (RES) val += res[idx];
        if (RELU) val = fmaxf(val, 0.f);
        if (OUTBF) ((u16*)outv)[idx] = f2bf(val);
        else       ((float*)outv)[idx] = val;
      }
    }
  }
}

// ---------------- MFMA attention, column(query-axis) softmax ----------------
// qkv: (B*T, 1152) bf16, q at col h*64, k at 384+h*64, v at 768+h*64
// out: (B*T, 384) bf16.  scale = 384^-0.5.
#define ASCALE 0.051031036307982884f

__global__ __launch_bounds__(1024) void attn_mfma(const u16* __restrict__ qkv,
                                                  u16* __restrict__ out) {
  // LDS: [0,36864) Ks(256x72 u16) then VT(64x264 u16);
  //      [36864,+20480) partials(16x256 f32) then P-stage(16 waves x 16x40 u16);
  //      [57344,+1024) gmax; [58368,+1024) linv
  __shared__ __align__(16) char lds_raw[36864 + 20480 + 2048];
  u16*   Ks       = (u16*)lds_raw;
  u16*   VT       = (u16*)lds_raw;
  float* partials = (float*)(lds_raw + 36864);
  u16*   stage    = (u16*)(lds_raw + 36864);
  float* gmax     = (float*)(lds_raw + 57344);
  float* linv     = (float*)(lds_raw + 58368);

  const int tid = threadIdx.x;
  const int lane = tid & 63;
  const int w = tid >> 6;           // wave 0..15 owns S rows [16w,16w+16)
  const int lm = lane & 15, qd = lane >> 4;
  const int b = blockIdx.x / NHH, h = blockIdx.x % NHH;
  const size_t rowbase = (size_t)b * TT;
  const u16* qp = qkv + rowbase * QKVLD + h * HSZ;
  const u16* kp = qp + 384;
  const u16* vp = qp + 768;

  // stage K rows into Ks (stride 72 u16 = 144B, 16B-aligned, 2-way banks on frag reads)
  {
    int s = tid >> 2, c4 = tid & 3;
    const u16* src = kp + (size_t)s * QKVLD;
    *(uint4*)&Ks[s * 72 + c4 * 8]       = *(const uint4*)(src + c4 * 8);
    *(uint4*)&Ks[s * 72 + (c4 + 4) * 8] = *(const uint4*)(src + (c4 + 4) * 8);
  }
  // Q fragments (A-layout: m=lm, k=qd*8+j) straight from global
  short8 qf0, qf1;
  {
    const u16* qrow = qp + (size_t)(16 * w + lm) * QKVLD + qd * 8;
    qf0 = *(const short8*)(qrow);
    qf1 = *(const short8*)(qrow + 32);
  }
  __syncthreads();

  floatx4 acc[16];
  floatx4 zero4 = {0.f, 0.f, 0.f, 0.f};
#pragma unroll
  for (int tc = 0; tc < 16; ++tc) acc[tc] = zero4;

  // S = Q K^T on causal tiles only (tc <= w)
#pragma unroll
  for (int tc = 0; tc < 16; ++tc) {
    if (tc <= w) {
      int sr = 16 * tc + lm;
      short8 kf0 = *(const short8*)&Ks[sr * 72 + qd * 8];
      short8 kf1 = *(const short8*)&Ks[sr * 72 + 32 + qd * 8];
      acc[tc] = __builtin_amdgcn_mfma_f32_16x16x32_bf16(qf0, kf0, acc[tc], 0, 0, 0);
      acc[tc] = __builtin_amdgcn_mfma_f32_16x16x32_bf16(qf1, kf1, acc[tc], 0, 0, 0);
    }
  }

  // scale + causal mask + per-wave column max (C/D: col=lm+16tc, row=16w+qd*4+r)
  const int rb = 16 * w + qd * 4;
  float pmax[16];
#pragma unroll
  for (int tc = 0; tc < 16; ++tc) {
    float m = -1e30f;
    if (tc <= w) {
      int sc = 16 * tc + lm;
#pragma unroll
      for (int r = 0; r < 4; ++r) {
        float vv = acc[tc][r] * ASCALE;
        vv = (rb + r >= sc) ? vv : -1e30f;
        acc[tc][r] = vv;
        m = fmaxf(m, vv);
      }
    }
    m = fmaxf(m, __shfl_xor(m, 16));
    m = fmaxf(m, __shfl_xor(m, 32));
    pmax[tc] = m;
  }
  if (lane < 16) {
#pragma unroll
    for (int tc = 0; tc < 16; ++tc) partials[w * 256 + tc * 16 + lane] = pmax[tc];
  }
  __syncthreads();
  if (tid < 256) {
    float m = partials[tid];
#pragma unroll
    for (int i = 1; i < 16; ++i) m = fmaxf(m, partials[i * 256 + tid]);
    gmax[tid] = m;
  }
  __syncthreads();

  // exp + per-wave column sum
  float psum[16];
#pragma unroll
  for (int tc = 0; tc < 16; ++tc) {
    float s = 0.f;
    if (tc <= w) {
      float gm = gmax[tc * 16 + lm];
#pragma unroll
      for (int r = 0; r < 4; ++r) {
        float e = (acc[tc][r] > -1e29f) ? __expf(acc[tc][r] - gm) : 0.f;
        acc[tc][r] = e;
        s += e;
      }
    }
    s += __shfl_xor(s, 16);
    s += __shfl_xor(s, 32);
    psum[tc] = s;
  }
  if (lane < 16) {
#pragma unroll
    for (int tc = 0; tc < 16; ++tc) partials[w * 256 + tc * 16 + lane] = psum[tc];
  }
  __syncthreads();
  if (tid < 256) {
    float s = partials[tid];
#pragma unroll
    for (int i = 1; i < 16; ++i) s += partials[i * 256 + tid];
    linv[tid] = 1.f / s;
  }
  __syncthreads();

  // stage V transposed: VT[d][s], stride 264 u16 (528B, 16B-aligned rows)
  {
    int s = tid >> 2, dg = (tid & 3) * 16;
    const u16* vrow = vp + (size_t)s * QKVLD + dg;
    u16 tmp[16];
    *(uint4*)&tmp[0] = *(const uint4*)(vrow);
    *(uint4*)&tmp[8] = *(const uint4*)(vrow + 8);
#pragma unroll
    for (int j = 0; j < 16; ++j) VT[(dg + j) * 264 + s] = tmp[j];
  }
  __syncthreads();

  // PV: per 32-col chunk, round-trip P through per-wave LDS stage (stride 40 u16)
  u16* mst = stage + w * 640;  // 1280B per wave
  floatx4 oacc[4];
#pragma unroll
  for (int nt = 0; nt < 4; ++nt) oacc[nt] = zero4;

#pragma unroll
  for (int c = 0; c < 8; ++c) {
    if (2 * c <= w) {
#pragma unroll
      for (int tt = 0; tt < 2; ++tt) {
        int tc = 2 * c + tt;
        float li = (tc <= w) ? linv[tc * 16 + lm] : 0.f;
#pragma unroll
        for (int r = 0; r < 4; ++r) {
          float pv = (tc <= w) ? acc[tc][r] * li : 0.f;
          mst[(qd * 4 + r) * 40 + tt * 16 + lm] = f2bf(pv);
        }
      }
      asm volatile("s_waitcnt lgkmcnt(0)" ::: "memory");
      short8 pf = *(const short8*)&mst[lm * 40 + qd * 8];
#pragma unroll
      for (int nt = 0; nt < 4; ++nt) {
        short8 vf = *(const short8*)&VT[(nt * 16 + lm) * 264 + c * 32 + qd * 8];
        oacc[nt] = __builtin_amdgcn_mfma_f32_16x16x32_bf16(pf, vf, oacc[nt], 0, 0, 0);
      }
      asm volatile("" ::: "memory");
    }
  }

  // store O (C/D layout), bf16 (B*T,384)
  u16* ob = out + rowbase * CCH + h * HSZ;
#pragma unroll
  for (int nt = 0; nt < 4; ++nt) {
#pragma unroll
    for (int r = 0; r < 4; ++r) {
      int t = 16 * w + qd * 4 + r;
      ob[(size_t)t * CCH + nt * 16 + lm] = f2bf(oacc[nt][r]);
    }
  }
}

// ---------------- launch ----------------
extern "C" void kernel_launch(void* const* d_in, const int* in_sizes, int n_in,
                              void* d_out, int out_size, void* d_ws, size_t ws_size,
                              hipStream_t stream) {
  const float* x     = (const float*)d_in[0];
  const float* wq    = (const float*)d_in[1];
  const float* wk    = (const float*)d_in[2];
  const float* wv    = (const float*)d_in[3];
  const float* wproj = (const float*)d_in[4];
  const float* bproj = (const float*)d_in[5];
  const float* w1    = (const float*)d_in[6];
  const float* b1    = (const float*)d_in[7];
  const float* w2    = (const float*)d_in[8];
  const float* b2    = (const float*)d_in[9];
  const float* ln1g  = (const float*)d_in[10];
  const float* ln1b  = (const float*)d_in[11];
  const float* ln2g  = (const float*)d_in[12];
  const float* ln2b  = (const float*)d_in[13];
  float* out = (float*)d_out;
  (void)in_sizes; (void)n_in; (void)out_size; (void)ws_size;

  char* ws = (char*)d_ws;
  size_t off = 0;
  auto alloc = [&](size_t bytes) -> void* {
    void* p = ws + off;
    off += (bytes + 255) & ~(size_t)255;
    return p;
  };

  u16* wqkv_t = (u16*)alloc((size_t)QKVLD * CCH * 2);         // (1152,384)
  u16* wp_t   = (u16*)alloc((size_t)CCH * CCH * 2);           // (384,384)
  u16* w1_t   = (u16*)alloc((size_t)4 * CCH * CCH * 2);       // (1536,384)
  u16* w2_t   = (u16*)alloc((size_t)CCH * 4 * CCH * 2);       // (384,1536)
  u16*   h_b  = (u16*)alloc((size_t)BTT * CCH * 2);           // LN1 / attn-out / LN2
  float* x2   = (float*)alloc((size_t)BTT * CCH * 4);         // fp32 residual stream
  u16*   qkv_b = (u16*)alloc((size_t)BTT * 4 * CCH * 2);      // (BT,1152) then u (BT,1536)
  u16*   u_b   = qkv_b;

  // weight repacks (transposed bf16)
  repack_qkv_t<<<(CCH * CCH + 255) / 256, 256, 0, stream>>>(wq, wk, wv, wqkv_t);
  repack_t<<<(CCH * CCH + 255) / 256, 256, 0, stream>>>(wproj, wp_t, CCH, CCH);
  repack_t<<<(CCH * 4 * CCH + 255) / 256, 256, 0, stream>>>(w1, w1_t, CCH, 4 * CCH);
  repack_t<<<(4 * CCH * CCH + 255) / 256, 256, 0, stream>>>(w2, w2_t, 4 * CCH, CCH);

  // LN1 -> h
  ln_kernel<<<BTT, 64, 0, stream>>>(x, ln1g, ln1b, h_b);

  // fused QKV: (BT,1152)
  gemm_mfma<0, 0, 0, 1><<<dim3(9, 256), 256, 0, stream>>>(h_b, wqkv_t, nullptr, nullptr,
                                                          qkv_b, BTT, QKVLD, CCH);
  // attention -> h_b (h dead)
  attn_mfma<<<BB * NHH, 1024, 0, stream>>>(qkv_b, h_b);

  // x2 = x + attn @ wproj + bproj
  gemm_mfma<1, 1, 0, 0><<<dim3(3, 256), 256, 0, stream>>>(h_b, wp_t, bproj, x, x2,
                                                          BTT, CCH, CCH);
  // LN2 -> h_b (attn dead)
  ln_kernel<<<BTT, 64, 0, stream>>>(x2, ln2g, ln2b, h_b);

  // u = relu(h2 @ w1 + b1): (BT,1536) over qkv_b region (qkv dead)
  gemm_mfma<1, 0, 1, 1><<<dim3(12, 256), 256, 0, stream>>>(h_b, w1_t, b1, nullptr, u_b,
                                                           BTT, 4 * CCH, CCH);
  // out = x2 + u @ w2 + b2
  gemm_mfma<1, 1, 0, 0><<<dim3(3, 256), 256, 0, stream>>>(u_b, w2_t, b2, x2, out,
                                                          BTT, CCH, 4 * CCH);
}

// Round 3
// 418.071 us; speedup vs baseline: 4.7533x; 1.0333x over previous
//
#include <hip/hip_runtime.h>

#define BB 128
#define TT 256
#define CCH 384
#define NHH 6
#define HSZ 64
#define BTT (BB*TT)
#define QKVLD 1152

typedef unsigned short u16;
typedef unsigned int   u32;
typedef __attribute__((ext_vector_type(8))) short  short8;   // 8 x bf16 (4 VGPR)
typedef __attribute__((ext_vector_type(4))) float  floatx4;  // MFMA C/D

__device__ __forceinline__ u16 f2bf(float f) {
  union { float f; u32 i; } v; v.f = f; u32 x = v.i;
  return (u16)((x + 0x7fffu + ((x >> 16) & 1u)) >> 16);
}
__device__ __forceinline__ float bf2f(u16 w) {
  union { u32 i; float f; } v; v.i = ((u32)w) << 16; return v.f;
}

// async global->LDS, 16B per lane; LDS dest is wave-uniform base + lane*16
__device__ __forceinline__ void gll16(const u16* g, u16* l) {
  __builtin_amdgcn_global_load_lds((const __attribute__((address_space(1))) void*)g,
                                   (__attribute__((address_space(3))) void*)l, 16, 0, 0);
}

// ---------------- LayerNorm: fp32/bf16 in -> bf16 out, one wave per row, 4 rows/block ----
template <int INBF>
__global__ __launch_bounds__(256) void ln_kernel(const void* __restrict__ xv,
                                                 const float* __restrict__ g,
                                                 const float* __restrict__ b,
                                                 u16* __restrict__ out) {
  int row = blockIdx.x * 4 + (threadIdx.x >> 6);
  int lane = threadIdx.x & 63;
  float vals[6];
  float sum = 0.f;
  if (INBF) {
    const u16* xr = (const u16*)xv + (size_t)row * CCH;
#pragma unroll
    for (int i = 0; i < 6; ++i) { vals[i] = bf2f(xr[lane + (i << 6)]); sum += vals[i]; }
  } else {
    const float* xr = (const float*)xv + (size_t)row * CCH;
#pragma unroll
    for (int i = 0; i < 6; ++i) { vals[i] = xr[lane + (i << 6)]; sum += vals[i]; }
  }
#pragma unroll
  for (int off = 32; off; off >>= 1) sum += __shfl_xor(sum, off);
  float mean = sum * (1.f / 384.f);
  float vs = 0.f;
#pragma unroll
  for (int i = 0; i < 6; ++i) { float d = vals[i] - mean; vs += d * d; }
#pragma unroll
  for (int off = 32; off; off >>= 1) vs += __shfl_xor(vs, off);
  float rinv = rsqrtf(vs * (1.f / 384.f) + 1e-5f);
  u16* orow = out + (size_t)row * CCH;
#pragma unroll
  for (int i = 0; i < 6; ++i) {
    int c = lane + (i << 6);
    orow[c] = f2bf((vals[i] - mean) * rinv * g[c] + b[c]);
  }
}

// ---------------- weight repacks: (K,N) fp32 -> (N,K) bf16 ----------------
__global__ void repack_t(const float* __restrict__ in, u16* __restrict__ out, int K, int N) {
  int idx = blockIdx.x * 256 + threadIdx.x;
  if (idx >= K * N) return;
  int n = idx / K, kk = idx % K;
  out[idx] = f2bf(in[(size_t)kk * N + n]);
}

// wq/wk/wv (H,C,HS) -> rows n=h*64+d of (384,384), into one (1152,384) buffer
__global__ void repack_qkv_t(const float* __restrict__ wq, const float* __restrict__ wk,
                             const float* __restrict__ wv, u16* __restrict__ o) {
  int idx = blockIdx.x * 256 + threadIdx.x;
  if (idx >= CCH * CCH) return;
  int n = idx / CCH, kk = idx % CCH;
  size_t src = ((size_t)(n >> 6) * CCH + kk) * 64 + (n & 63);
  o[idx]                 = f2bf(wq[src]);
  o[idx + CCH * CCH]     = f2bf(wk[src]);
  o[idx + 2 * CCH * CCH] = f2bf(wv[src]);
}

// ---- MFMA GEMM: C[M,N] = A[M,K] * W[N,K]^T, 128x128 tile, BK=32, double-buffered ----
template <int BIAS, int RES, int RELU, int OUTBF, int RESBF>
__global__ __launch_bounds__(256) void gemm_mfma(const u16* __restrict__ A,
                                                 const u16* __restrict__ W,
                                                 const float* __restrict__ bias,
                                                 const void* __restrict__ resv,
                                                 void* __restrict__ outv,
                                                 int M, int N, int K) {
  __shared__ __align__(16) u16 As[2][128 * 32];
  __shared__ __align__(16) u16 Bs[2][128 * 32];
  const int tid = threadIdx.x;
  const int lane = tid & 63;
  const int w = tid >> 6;
  const int wr = w >> 1, wc = w & 1;
  const int m0 = blockIdx.y * 128, n0 = blockIdx.x * 128;
  const int lm = lane & 15, qd = lane >> 4;

  floatx4 acc[4][4];
  floatx4 zero4 = {0.f, 0.f, 0.f, 0.f};
#pragma unroll
  for (int i = 0; i < 4; ++i)
#pragma unroll
    for (int j = 0; j < 4; ++j) acc[i][j] = zero4;

  // loader: wave w stages rows [32w,32w+32); chunk = slot ^ ((row>>1)&3) (XOR swizzle)
  const int r0 = w * 32 + (lane >> 2);
  const int c0 = (lane & 3) ^ ((r0 >> 1) & 3);
  const int r1 = r0 + 16;
  const int c1 = (lane & 3) ^ ((r1 >> 1) & 3);
  const u16* a0 = A + (size_t)(m0 + r0) * K + c0 * 8;
  const u16* a1 = A + (size_t)(m0 + r1) * K + c1 * 8;
  const u16* b0 = W + (size_t)(n0 + r0) * K + c0 * 8;
  const u16* b1 = W + (size_t)(n0 + r1) * K + c1 * 8;

  // prologue: stage k0=0 into buffer 0
  gll16(a0, &As[0][w * 1024]);
  gll16(a1, &As[0][w * 1024 + 512]);
  gll16(b0, &Bs[0][w * 1024]);
  gll16(b1, &Bs[0][w * 1024 + 512]);

  int ib = 0;
  for (int k0 = 0; k0 < K; k0 += 32, ib ^= 1) {
    __syncthreads();  // drains prefetch issued a full compute-phase ago
    int kn = k0 + 32;
    if (kn < K) {     // prefetch next step into the other buffer
      int nb = ib ^ 1;
      gll16(a0 + kn, &As[nb][w * 1024]);
      gll16(a1 + kn, &As[nb][w * 1024 + 512]);
      gll16(b0 + kn, &Bs[nb][w * 1024]);
      gll16(b1 + kn, &Bs[nb][w * 1024 + 512]);
    }
    short8 af[4], bf[4];
#pragma unroll
    for (int i = 0; i < 4; ++i) {
      int rm = 64 * wr + 16 * i + lm;
      af[i] = *(const short8*)&As[ib][rm * 32 + (qd ^ ((rm >> 1) & 3)) * 8];
      int rn = 64 * wc + 16 * i + lm;
      bf[i] = *(const short8*)&Bs[ib][rn * 32 + (qd ^ ((rn >> 1) & 3)) * 8];
    }
#pragma unroll
    for (int i = 0; i < 4; ++i)
#pragma unroll
      for (int j = 0; j < 4; ++j)
        acc[i][j] = __builtin_amdgcn_mfma_f32_16x16x32_bf16(af[i], bf[j], acc[i][j], 0, 0, 0);
  }

  // epilogue: C/D layout col=lm, row=qd*4+r
#pragma unroll
  for (int i = 0; i < 4; ++i) {
    int row0 = m0 + 64 * wr + 16 * i + qd * 4;
#pragma unroll
    for (int j = 0; j < 4; ++j) {
      int col = n0 + 64 * wc + 16 * j + lm;
      float bb = 0.f;
      if (BIAS) bb = bias[col];
#pragma unroll
      for (int r = 0; r < 4; ++r) {
        size_t idx = (size_t)(row0 + r) * N + col;
        float val = acc[i][j][r] + bb;
        if (RES) val += RESBF ? bf2f(((const u16*)resv)[idx]) : ((const float*)resv)[idx];
        if (RELU) val = fmaxf(val, 0.f);
        if (OUTBF) ((u16*)outv)[idx] = f2bf(val);
        else       ((float*)outv)[idx] = val;
      }
    }
  }
}

// ---------------- MFMA attention, column(query-axis) softmax ----------------
// qkv: (B*T, 1152) bf16, q at col h*64, k at 384+h*64, v at 768+h*64
// out: (B*T, 384) bf16.  scale = 384^-0.5.
#define ASCALE 0.051031036307982884f

__global__ __launch_bounds__(1024) void attn_mfma(const u16* __restrict__ qkv,
                                                  u16* __restrict__ out) {
  __shared__ __align__(16) char lds_raw[36864 + 20480 + 2048];
  u16*   Ks       = (u16*)lds_raw;
  u16*   VT       = (u16*)lds_raw;
  float* partials = (float*)(lds_raw + 36864);
  u16*   stage    = (u16*)(lds_raw + 36864);
  float* gmax     = (float*)(lds_raw + 57344);
  float* linv     = (float*)(lds_raw + 58368);

  const int tid = threadIdx.x;
  const int lane = tid & 63;
  const int w = tid >> 6;           // wave 0..15 owns S rows [16w,16w+16)
  const int lm = lane & 15, qd = lane >> 4;
  const int b = blockIdx.x / NHH, h = blockIdx.x % NHH;
  const size_t rowbase = (size_t)b * TT;
  const u16* qp = qkv + rowbase * QKVLD + h * HSZ;
  const u16* kp = qp + 384;
  const u16* vp = qp + 768;

  // stage K rows into Ks (stride 72 u16)
  {
    int s = tid >> 2, c4 = tid & 3;
    const u16* src = kp + (size_t)s * QKVLD;
    *(uint4*)&Ks[s * 72 + c4 * 8]       = *(const uint4*)(src + c4 * 8);
    *(uint4*)&Ks[s * 72 + (c4 + 4) * 8] = *(const uint4*)(src + (c4 + 4) * 8);
  }
  short8 qf0, qf1;
  {
    const u16* qrow = qp + (size_t)(16 * w + lm) * QKVLD + qd * 8;
    qf0 = *(const short8*)(qrow);
    qf1 = *(const short8*)(qrow + 32);
  }
  __syncthreads();

  floatx4 acc[16];
  floatx4 zero4 = {0.f, 0.f, 0.f, 0.f};
#pragma unroll
  for (int tc = 0; tc < 16; ++tc) acc[tc] = zero4;

#pragma unroll
  for (int tc = 0; tc < 16; ++tc) {
    if (tc <= w) {
      int sr = 16 * tc + lm;
      short8 kf0 = *(const short8*)&Ks[sr * 72 + qd * 8];
      short8 kf1 = *(const short8*)&Ks[sr * 72 + 32 + qd * 8];
      acc[tc] = __builtin_amdgcn_mfma_f32_16x16x32_bf16(qf0, kf0, acc[tc], 0, 0, 0);
      acc[tc] = __builtin_amdgcn_mfma_f32_16x16x32_bf16(qf1, kf1, acc[tc], 0, 0, 0);
    }
  }

  const int rb = 16 * w + qd * 4;
  float pmax[16];
#pragma unroll
  for (int tc = 0; tc < 16; ++tc) {
    float m = -1e30f;
    if (tc <= w) {
      int sc = 16 * tc + lm;
#pragma unroll
      for (int r = 0; r < 4; ++r) {
        float vv = acc[tc][r] * ASCALE;
        vv = (rb + r >= sc) ? vv : -1e30f;
        acc[tc][r] = vv;
        m = fmaxf(m, vv);
      }
    }
    m = fmaxf(m, __shfl_xor(m, 16));
    m = fmaxf(m, __shfl_xor(m, 32));
    pmax[tc] = m;
  }
  if (lane < 16) {
#pragma unroll
    for (int tc = 0; tc < 16; ++tc) partials[w * 256 + tc * 16 + lane] = pmax[tc];
  }
  __syncthreads();
  if (tid < 256) {
    float m = partials[tid];
#pragma unroll
    for (int i = 1; i < 16; ++i) m = fmaxf(m, partials[i * 256 + tid]);
    gmax[tid] = m;
  }
  __syncthreads();

  float psum[16];
#pragma unroll
  for (int tc = 0; tc < 16; ++tc) {
    float s = 0.f;
    if (tc <= w) {
      float gm = gmax[tc * 16 + lm];
#pragma unroll
      for (int r = 0; r < 4; ++r) {
        float e = (acc[tc][r] > -1e29f) ? __expf(acc[tc][r] - gm) : 0.f;
        acc[tc][r] = e;
        s += e;
      }
    }
    s += __shfl_xor(s, 16);
    s += __shfl_xor(s, 32);
    psum[tc] = s;
  }
  if (lane < 16) {
#pragma unroll
    for (int tc = 0; tc < 16; ++tc) partials[w * 256 + tc * 16 + lane] = psum[tc];
  }
  __syncthreads();
  if (tid < 256) {
    float s = partials[tid];
#pragma unroll
    for (int i = 1; i < 16; ++i) s += partials[i * 256 + tid];
    linv[tid] = 1.f / s;
  }
  __syncthreads();

  // stage V transposed: VT[d][s], stride 264 u16
  {
    int s = tid >> 2, dg = (tid & 3) * 16;
    const u16* vrow = vp + (size_t)s * QKVLD + dg;
    u16 tmp[16];
    *(uint4*)&tmp[0] = *(const uint4*)(vrow);
    *(uint4*)&tmp[8] = *(const uint4*)(vrow + 8);
#pragma unroll
    for (int j = 0; j < 16; ++j) VT[(dg + j) * 264 + s] = tmp[j];
  }
  __syncthreads();

  u16* mst = stage + w * 640;
  floatx4 oacc[4];
#pragma unroll
  for (int nt = 0; nt < 4; ++nt) oacc[nt] = zero4;

#pragma unroll
  for (int c = 0; c < 8; ++c) {
    if (2 * c <= w) {
#pragma unroll
      for (int tt = 0; tt < 2; ++tt) {
        int tc = 2 * c + tt;
        float li = (tc <= w) ? linv[tc * 16 + lm] : 0.f;
#pragma unroll
        for (int r = 0; r < 4; ++r) {
          float pv = (tc <= w) ? acc[tc][r] * li : 0.f;
          mst[(qd * 4 + r) * 40 + tt * 16 + lm] = f2bf(pv);
        }
      }
      asm volatile("s_waitcnt lgkmcnt(0)" ::: "memory");
      short8 pf = *(const short8*)&mst[lm * 40 + qd * 8];
#pragma unroll
      for (int nt = 0; nt < 4; ++nt) {
        short8 vf = *(const short8*)&VT[(nt * 16 + lm) * 264 + c * 32 + qd * 8];
        oacc[nt] = __builtin_amdgcn_mfma_f32_16x16x32_bf16(pf, vf, oacc[nt], 0, 0, 0);
      }
      asm volatile("" ::: "memory");
    }
  }

  u16* ob = out + rowbase * CCH + h * HSZ;
#pragma unroll
  for (int nt = 0; nt < 4; ++nt) {
#pragma unroll
    for (int r = 0; r < 4; ++r) {
      int t = 16 * w + qd * 4 + r;
      ob[(size_t)t * CCH + nt * 16 + lm] = f2bf(oacc[nt][r]);
    }
  }
}

// ---------------- launch ----------------
extern "C" void kernel_launch(void* const* d_in, const int* in_sizes, int n_in,
                              void* d_out, int out_size, void* d_ws, size_t ws_size,
                              hipStream_t stream) {
  const float* x     = (const float*)d_in[0];
  const float* wq    = (const float*)d_in[1];
  const float* wk    = (const float*)d_in[2];
  const float* wv    = (const float*)d_in[3];
  const float* wproj = (const float*)d_in[4];
  const float* bproj = (const float*)d_in[5];
  const float* w1    = (const float*)d_in[6];
  const float* b1    = (const float*)d_in[7];
  const float* w2    = (const float*)d_in[8];
  const float* b2    = (const float*)d_in[9];
  const float* ln1g  = (const float*)d_in[10];
  const float* ln1b  = (const float*)d_in[11];
  const float* ln2g  = (const float*)d_in[12];
  const float* ln2b  = (const float*)d_in[13];
  float* out = (float*)d_out;
  (void)in_sizes; (void)n_in; (void)out_size; (void)ws_size;

  char* ws = (char*)d_ws;
  size_t off = 0;
  auto alloc = [&](size_t bytes) -> void* {
    void* p = ws + off;
    off += (bytes + 255) & ~(size_t)255;
    return p;
  };

  u16* wqkv_t = (u16*)alloc((size_t)QKVLD * CCH * 2);         // (1152,384)
  u16* wp_t   = (u16*)alloc((size_t)CCH * CCH * 2);           // (384,384)
  u16* w1_t   = (u16*)alloc((size_t)4 * CCH * CCH * 2);       // (1536,384)
  u16* w2_t   = (u16*)alloc((size_t)CCH * 4 * CCH * 2);       // (384,1536)
  u16*   h_b  = (u16*)alloc((size_t)BTT * CCH * 2);           // LN1 / attn-out / LN2
  u16*   x2   = (u16*)alloc((size_t)BTT * CCH * 2);           // bf16 residual stream
  u16*   qkv_b = (u16*)alloc((size_t)BTT * 4 * CCH * 2);      // (BT,1152) then u (BT,1536)
  u16*   u_b   = qkv_b;

  repack_qkv_t<<<(CCH * CCH + 255) / 256, 256, 0, stream>>>(wq, wk, wv, wqkv_t);
  repack_t<<<(CCH * CCH + 255) / 256, 256, 0, stream>>>(wproj, wp_t, CCH, CCH);
  repack_t<<<(CCH * 4 * CCH + 255) / 256, 256, 0, stream>>>(w1, w1_t, CCH, 4 * CCH);
  repack_t<<<(4 * CCH * CCH + 255) / 256, 256, 0, stream>>>(w2, w2_t, 4 * CCH, CCH);

  // LN1 -> h
  ln_kernel<0><<<BTT / 4, 256, 0, stream>>>(x, ln1g, ln1b, h_b);

  // fused QKV: (BT,1152)
  gemm_mfma<0, 0, 0, 1, 0><<<dim3(9, 256), 256, 0, stream>>>(h_b, wqkv_t, nullptr, nullptr,
                                                             qkv_b, BTT, QKVLD, CCH);
  // attention -> h_b (h dead)
  attn_mfma<<<BB * NHH, 1024, 0, stream>>>(qkv_b, h_b);

  // x2 = x + attn @ wproj + bproj  (bf16 out)
  gemm_mfma<1, 1, 0, 1, 0><<<dim3(3, 256), 256, 0, stream>>>(h_b, wp_t, bproj, x, x2,
                                                             BTT, CCH, CCH);
  // LN2 -> h_b (attn dead)
  ln_kernel<1><<<BTT / 4, 256, 0, stream>>>(x2, ln2g, ln2b, h_b);

  // u = relu(h2 @ w1 + b1): (BT,1536)
  gemm_mfma<1, 0, 1, 1, 0><<<dim3(12, 256), 256, 0, stream>>>(h_b, w1_t, b1, nullptr, u_b,
                                                              BTT, 4 * CCH, CCH);
  // out = x2 + u @ w2 + b2  (fp32 out, bf16 res)
  gemm_mfma<1, 1, 0, 0, 1><<<dim3(3, 256), 256, 0, stream>>>(u_b, w2_t, b2, x2, out,
                                                             BTT, CCH, 4 * CCH);
}